// Round 3
// baseline (109.579 us; speedup 1.0000x reference)
//
#include <hip/hip_runtime.h>

// DepthDeformConv — round 11: barrier-free tap loop.
//   r10 A/B: stencil prefetch -5.3us -> exposed latency confirmed. Remaining
//   structural stall: 9 per-tap __syncthreads (wtap dbuf) each compile to
//   full vmcnt(0)+lgkmcnt(0) drains before s_barrier, serializing taps at
//   2 waves/SIMD. Fix: drop wtap entirely; afrag weights load from global
//   (72KB wT2 is L2-resident; VMEM pipe is idle in the tap loop since r9
//   moved corners to LDS). One barrier total (after window staging); the
//   unrolled 9-tap body becomes a barrier-free LDS||VMEM||VALU||MFMA stream
//   the compiler can pipeline. LDS 144->128KB; launch_bounds(512,2) exposes
//   the true occupancy so regalloc can use up to 256 VGPR.

typedef __attribute__((ext_vector_type(8))) short bf16x8;
typedef __attribute__((ext_vector_type(4))) float f32x4;
typedef __attribute__((ext_vector_type(4))) unsigned int u32x4;

#define HH 128
#define WW 128
#define CC 64
#define OO 64
#define HW (128 * 128)

__device__ __forceinline__ unsigned f32_to_bf16_rne(float f) {
    unsigned u = __float_as_uint(f);
    return (u + 0x7FFFu + ((u >> 16) & 1u)) >> 16;
}

// ---------------- kernel 1: fused NCHW->NHWC bf16 + weight repack ----------------
__global__ __launch_bounds__(256)
void prep_fused11(const float* __restrict__ input,
                  unsigned short* __restrict__ nhwc,
                  const float* __restrict__ weight,
                  unsigned short* __restrict__ wT2)
{
    __shared__ unsigned tile[64][33];
    const int tid = threadIdx.x;
    const int blk = blockIdx.x;

    if (blk >= 2048) {
        // weight repack: wT2[(kt*8 + c8)*64 + o] = bf16 w for ch c8*8..+7, tap kt
        const int d  = (blk - 2048) * 256 + tid;    // 0..4607
        const int o  = d & 63;
        const int k8 = d >> 6;                      // 0..71
        const int kt = k8 >> 3;
        const int c8 = k8 & 7;
        u32x4 pk;
        #pragma unroll
        for (int jj = 0; jj < 4; ++jj) {
            unsigned lo = f32_to_bf16_rne(weight[o * 576 + (c8 * 8 + 2 * jj)     * 9 + kt]);
            unsigned hi = f32_to_bf16_rne(weight[o * 576 + (c8 * 8 + 2 * jj + 1) * 9 + kt]);
            pk[jj] = lo | (hi << 16);
        }
        *(u32x4*)(wT2 + (size_t)d * 8) = pk;
        return;
    }

    const int b  = blk >> 9;
    const int y  = (blk >> 2) & 127;
    const int xbase = (blk & 3) * 32;
    #pragma unroll
    for (int it = 0; it < 8; ++it) {
        int flat = it * 256 + tid;          // 0..2047
        int c = flat >> 5, x = flat & 31;
        float v = input[((b * 64 + c) * 128 + y) * 128 + xbase + x];
        tile[c][x] = f32_to_bf16_rne(v);
    }
    __syncthreads();
    {
        int x = tid >> 3, cg = tid & 7;     // 32x * 8 channel-groups
        unsigned r0 = tile[cg * 8 + 0][x], r1 = tile[cg * 8 + 1][x];
        unsigned r2 = tile[cg * 8 + 2][x], r3 = tile[cg * 8 + 3][x];
        unsigned r4 = tile[cg * 8 + 4][x], r5 = tile[cg * 8 + 5][x];
        unsigned r6 = tile[cg * 8 + 6][x], r7 = tile[cg * 8 + 7][x];
        u32x4 pk;
        pk[0] = r0 | (r1 << 16); pk[1] = r2 | (r3 << 16);
        pk[2] = r4 | (r5 << 16); pk[3] = r6 | (r7 << 16);
        *(u32x4*)(nhwc + ((size_t)((b * 128 + y) * 128 + xbase + x)) * 64 + cg * 8) = pk;
    }
}

// ---------------- kernel 2: fused sample + MFMA, barrier-free taps ----------------
__global__ __launch_bounds__(512, 2)
void ddc_win11(const unsigned short* __restrict__ nhwc,
               const unsigned short* __restrict__ wT2,
               const float* __restrict__ offset,
               const float* __restrict__ mask,
               const float* __restrict__ bias,
               float* __restrict__ out)
{
    // 8-row bf16 NHWC window, chunk-swizzled: LDS u32x4 index
    //   idx(slot,x,c8pos) = slot*1024 + x*8 + c8pos, holding source chunk
    //   c8pos ^ (x&7). Reader at chunk ch uses pos = ch ^ (x&7).
    __shared__ u32x4 win[8192];            // 128 KB (only LDS in kernel)

    const int blk0 = blockIdx.x;           // 512 = 4b * 128h
    const int blk  = (blk0 & 7) * 64 + (blk0 >> 3);   // XCD-chunked swizzle
    const int b    = blk >> 7;
    const int h    = blk & 127;
    const int tid  = threadIdx.x;
    const int wave = tid >> 6;             // 8 pixel groups
    const int lane = tid & 63;
    const int l15  = lane & 15;            // pixel within group / o-row (A)
    const int kq   = lane >> 4;            // k-chunk quad (0..3)
    const int wpix = wave * 16 + l15;      // w coordinate (full 128 row)

    f32x4 acc[4];
    #pragma unroll
    for (int mt = 0; mt < 4; ++mt) acc[mt] = (f32x4){0.f, 0.f, 0.f, 0.f};

    const unsigned short* nb = nhwc + (size_t)b * HW * CC;
    const u32x4* wsrc = (const u32x4*)wT2;

    // ---- prefetch all per-pixel stencil scalars (27 coalesced loads) ----
    float oyv[9], oxv[9], mv[9];
    #pragma unroll
    for (int kt = 0; kt < 9; ++kt) {
        oyv[kt] = offset[((b * 18 + 2 * kt)     * 128 + h) * 128 + wpix];
        oxv[kt] = offset[((b * 18 + 2 * kt + 1) * 128 + h) * 128 + wpix];
        mv[kt]  = mask  [((b * 9  + kt)         * 128 + h) * 128 + wpix];
    }

    // ---- stage window rows h-3..h+4 (swizzled source, linear LDS dest) ----
    #pragma unroll
    for (int i = 0; i < 16; ++i) {
        const int slot = i >> 1;                      // uniform per i
        const int y = h - 3 + slot;
        if (y >= 0 && y < HH) {
            const int q  = ((i & 1) << 9) + tid;      // 0..1023 within row
            const int x  = q >> 3;
            const int c8 = q & 7;
            win[slot * 1024 + q] =
                *(const u32x4*)(nb + ((size_t)(y * WW + x)) * CC + ((c8 ^ (x & 7)) << 3));
        }
    }
    __syncthreads();                                  // the ONLY barrier

    auto do_tap = [&](int kt, float oy, float ox, float m) {
        const float py = (float)(h - 1 + kt / 3) + oy;
        const float px = (float)(wpix - 1 + kt % 3) + ox;
        const float y0f = floorf(py), x0f = floorf(px);
        const int y0 = (int)y0f, x0 = (int)x0f;
        const float wy = py - y0f, wx = px - x0f;
        const int y1 = y0 + 1, x1 = x0 + 1;
        const bool vy0 = (y0 >= 0) & (y0 < HH);
        const bool vy1 = (y1 >= 0) & (y1 < HH);
        const bool vx0 = (x0 >= 0) & (x0 < WW);
        const bool vx1 = (x1 >= 0) & (x1 < WW);
        const int y0c = min(max(y0, 0), HH - 1), y1c = min(max(y1, 0), HH - 1);
        const int x0c = min(max(x0, 0), WW - 1), x1c = min(max(x1, 0), WW - 1);
        const float wy1 = 1.f - wy, wx1 = 1.f - wx;
        const float c00 = (vy0 && vx0) ? wy1 * wx1 * m : 0.f;
        const float c01 = (vy0 && vx1) ? wy1 * wx  * m : 0.f;
        const float c10 = (vy1 && vx0) ? wy  * wx1 * m : 0.f;
        const float c11 = (vy1 && vx1) ? wy  * wx  * m : 0.f;

        // window slots (clamped for LDS safety; oow lanes reload from global)
        const int s0 = y0c - (h - 3), s1 = y1c - (h - 3);
        const bool in0 = ((unsigned)s0 < 8u);
        const bool in1 = ((unsigned)s1 < 8u);
        const int r0 = (in0 ? s0 : 0) * 1024;
        const int r1 = (in1 ? s1 : 0) * 1024;
        const int bx0 = x0c * 8, sx0 = x0c & 7;
        const int bx1 = x1c * 8, sx1 = x1c & 7;

        #pragma unroll
        for (int ks = 0; ks < 2; ++ks) {
            const int ch = ks * 4 + kq;       // this lane's 8-channel chunk

            u32x4 w00 = win[r0 + bx0 + (ch ^ sx0)];
            u32x4 w01 = win[r0 + bx1 + (ch ^ sx1)];
            u32x4 w10 = win[r1 + bx0 + (ch ^ sx0)];
            u32x4 w11 = win[r1 + bx1 + (ch ^ sx1)];
            if (!in0) {                       // rare: |oy| past window
                w00 = *(const u32x4*)(nb + ((size_t)y0c * WW + x0c) * CC + ch * 8);
                w01 = *(const u32x4*)(nb + ((size_t)y0c * WW + x1c) * CC + ch * 8);
            }
            if (!in1) {
                w10 = *(const u32x4*)(nb + ((size_t)y1c * WW + x0c) * CC + ch * 8);
                w11 = *(const u32x4*)(nb + ((size_t)y1c * WW + x1c) * CC + ch * 8);
            }

            u32x4 pk;
            #pragma unroll
            for (int j = 0; j < 4; ++j) {
                const float a0 = __uint_as_float(w00[j] << 16);
                const float a1 = __uint_as_float(w00[j] & 0xFFFF0000u);
                const float b0 = __uint_as_float(w01[j] << 16);
                const float b1 = __uint_as_float(w01[j] & 0xFFFF0000u);
                const float d0 = __uint_as_float(w10[j] << 16);
                const float d1 = __uint_as_float(w10[j] & 0xFFFF0000u);
                const float e0 = __uint_as_float(w11[j] << 16);
                const float e1 = __uint_as_float(w11[j] & 0xFFFF0000u);
                const float s0f = c00 * a0 + c01 * b0 + c10 * d0 + c11 * e0;
                const float s1f = c00 * a1 + c01 * b1 + c10 * d1 + c11 * e1;
                pk[j] = f32_to_bf16_rne(s0f) | (f32_to_bf16_rne(s1f) << 16);
            }
            const bf16x8 bfrag = __builtin_bit_cast(bf16x8, pk);

            // A-fragments straight from global (wT2 is 72KB, L2-resident;
            // VMEM pipe is idle in the tap loop — corners come from LDS)
            #pragma unroll
            for (int mt = 0; mt < 4; ++mt) {
                const bf16x8 afrag = __builtin_bit_cast(bf16x8,
                    wsrc[(kt * 8 + ks * 4 + kq) * 64 + mt * 16 + l15]);
                acc[mt] = __builtin_amdgcn_mfma_f32_16x16x32_bf16(afrag, bfrag, acc[mt], 0, 0, 0);
            }
        }
    };

    // ---- K loop: fully unrolled, barrier-free ----
    #pragma unroll
    for (int kt = 0; kt < 9; ++kt) {
        do_tap(kt, oyv[kt], oxv[kt], mv[kt]);
    }

    // ---- epilogue: C/D layout col=lane&15 (pixel), row=kq*4+reg (o) ----
    #pragma unroll
    for (int mt = 0; mt < 4; ++mt) {
        const f32x4 bv = *(const f32x4*)(bias + mt * 16 + kq * 4);
        #pragma unroll
        for (int r = 0; r < 4; ++r) {
            const int o = mt * 16 + kq * 4 + r;
            out[((b * 64 + o) * 128 + h) * 128 + wpix] = acc[mt][r] + bv[r];
        }
    }
}

extern "C" void kernel_launch(void* const* d_in, const int* in_sizes, int n_in,
                              void* d_out, int out_size, void* d_ws, size_t ws_size,
                              hipStream_t stream)
{
    const float* input  = (const float*)d_in[0];
    // d_in[1] = depth, unused by the reference
    const float* offset = (const float*)d_in[2];
    const float* mask   = (const float*)d_in[3];
    const float* weight = (const float*)d_in[4];
    const float* bias   = (const float*)d_in[5];
    float* out = (float*)d_out;

    unsigned short* nhwc = (unsigned short*)d_ws;                    // 8.39 MB
    unsigned short* wT2  = nhwc + (size_t)4 * HW * CC;               // 73728 B

    prep_fused11<<<dim3(2066), dim3(256), 0, stream>>>(input, nhwc, weight, wT2);
    ddc_win11<<<dim3(512), dim3(512), 0, stream>>>(nhwc, wT2, offset, mask, bias, out);
}

// Round 4
// 105.398 us; speedup vs baseline: 1.0397x; 1.0397x over previous
//
#include <hip/hip_runtime.h>

// DepthDeformConv — round 12: 2-row blocks, 16 waves sharing one window.
//   r11 null (barrier removal ±0) + r10 win (latency prefetch -5.3) + pipe
//   arithmetic (VALU 18%, LDS 21% of round time) -> main is latency-bound
//   at 2 waves/SIMD (128KB LDS = 1 block/CU). Fix: process 2 h-rows per
//   block: 1024 thr / 16 waves share a 9-row 144KB window -> 4 waves/SIMD
//   (2x latency hiding), 256 blocks = exactly 1/CU, single round, staging
//   traffic halved. VGPR must be <=128 (16 resident waves) - prefetch 27 +
//   acc 16 + working set should fit. Numerics bit-identical to r9-r11.

typedef __attribute__((ext_vector_type(8))) short bf16x8;
typedef __attribute__((ext_vector_type(4))) float f32x4;
typedef __attribute__((ext_vector_type(4))) unsigned int u32x4;

#define HH 128
#define WW 128
#define CC 64
#define OO 64
#define HW (128 * 128)

__device__ __forceinline__ unsigned f32_to_bf16_rne(float f) {
    unsigned u = __float_as_uint(f);
    return (u + 0x7FFFu + ((u >> 16) & 1u)) >> 16;
}

// ---------------- kernel 1: fused NCHW->NHWC bf16 + weight repack ----------------
__global__ __launch_bounds__(256)
void prep_fused12(const float* __restrict__ input,
                  unsigned short* __restrict__ nhwc,
                  const float* __restrict__ weight,
                  unsigned short* __restrict__ wT2)
{
    __shared__ unsigned tile[64][33];
    const int tid = threadIdx.x;
    const int blk = blockIdx.x;

    if (blk >= 2048) {
        // weight repack: wT2[(kt*8 + c8)*64 + o] = bf16 w for ch c8*8..+7, tap kt
        const int d  = (blk - 2048) * 256 + tid;    // 0..4607
        const int o  = d & 63;
        const int k8 = d >> 6;                      // 0..71
        const int kt = k8 >> 3;
        const int c8 = k8 & 7;
        u32x4 pk;
        #pragma unroll
        for (int jj = 0; jj < 4; ++jj) {
            unsigned lo = f32_to_bf16_rne(weight[o * 576 + (c8 * 8 + 2 * jj)     * 9 + kt]);
            unsigned hi = f32_to_bf16_rne(weight[o * 576 + (c8 * 8 + 2 * jj + 1) * 9 + kt]);
            pk[jj] = lo | (hi << 16);
        }
        *(u32x4*)(wT2 + (size_t)d * 8) = pk;
        return;
    }

    const int b  = blk >> 9;
    const int y  = (blk >> 2) & 127;
    const int xbase = (blk & 3) * 32;
    #pragma unroll
    for (int it = 0; it < 8; ++it) {
        int flat = it * 256 + tid;          // 0..2047
        int c = flat >> 5, x = flat & 31;
        float v = input[((b * 64 + c) * 128 + y) * 128 + xbase + x];
        tile[c][x] = f32_to_bf16_rne(v);
    }
    __syncthreads();
    {
        int x = tid >> 3, cg = tid & 7;     // 32x * 8 channel-groups
        unsigned r0 = tile[cg * 8 + 0][x], r1 = tile[cg * 8 + 1][x];
        unsigned r2 = tile[cg * 8 + 2][x], r3 = tile[cg * 8 + 3][x];
        unsigned r4 = tile[cg * 8 + 4][x], r5 = tile[cg * 8 + 5][x];
        unsigned r6 = tile[cg * 8 + 6][x], r7 = tile[cg * 8 + 7][x];
        u32x4 pk;
        pk[0] = r0 | (r1 << 16); pk[1] = r2 | (r3 << 16);
        pk[2] = r4 | (r5 << 16); pk[3] = r6 | (r7 << 16);
        *(u32x4*)(nhwc + ((size_t)((b * 128 + y) * 128 + xbase + x)) * 64 + cg * 8) = pk;
    }
}

// ---------------- kernel 2: fused sample + MFMA, 2-row / 16-wave blocks ----------------
__global__ __launch_bounds__(1024, 4)
void ddc_win12(const unsigned short* __restrict__ nhwc,
               const unsigned short* __restrict__ wT2,
               const float* __restrict__ offset,
               const float* __restrict__ mask,
               const float* __restrict__ bias,
               float* __restrict__ out)
{
    // 9-row bf16 NHWC window, chunk-swizzled: LDS u32x4 index
    //   idx(slot,x,c8pos) = slot*1024 + x*8 + c8pos, holding source chunk
    //   c8pos ^ (x&7). Reader at chunk ch uses pos = ch ^ (x&7).
    __shared__ u32x4 win[9216];            // 144 KB (only LDS in kernel)

    const int blk0 = blockIdx.x;           // 256 = 4b * 64 h-pairs
    const int blk  = (blk0 & 7) * 32 + (blk0 >> 3);   // XCD-chunked swizzle
    const int b    = blk >> 6;
    const int h0   = (blk & 63) * 2;
    const int ys   = h0 - 3;               // window start row
    const int tid  = threadIdx.x;
    const int wave = tid >> 6;             // 16 waves
    const int lane = tid & 63;
    const int l15  = lane & 15;            // pixel within group / o-row (A)
    const int kq   = lane >> 4;            // k-chunk quad (0..3)
    const int h    = h0 + (wave >> 3);     // waves 0-7 -> h0, 8-15 -> h0+1
    const int wpix = (wave & 7) * 16 + l15;

    f32x4 acc[4];
    #pragma unroll
    for (int mt = 0; mt < 4; ++mt) acc[mt] = (f32x4){0.f, 0.f, 0.f, 0.f};

    const unsigned short* nb = nhwc + (size_t)b * HW * CC;
    const u32x4* wsrc = (const u32x4*)wT2;

    // ---- prefetch all per-pixel stencil scalars (27 coalesced loads) ----
    float oyv[9], oxv[9], mv[9];
    #pragma unroll
    for (int kt = 0; kt < 9; ++kt) {
        oyv[kt] = offset[((b * 18 + 2 * kt)     * 128 + h) * 128 + wpix];
        oxv[kt] = offset[((b * 18 + 2 * kt + 1) * 128 + h) * 128 + wpix];
        mv[kt]  = mask  [((b * 9  + kt)         * 128 + h) * 128 + wpix];
    }

    // ---- stage window rows ys..ys+8 (swizzled source, linear LDS dest) ----
    #pragma unroll
    for (int slot = 0; slot < 9; ++slot) {
        const int y = ys + slot;
        if (y >= 0 && y < HH) {
            const int q  = tid;                       // 0..1023 = one full row
            const int x  = q >> 3;
            const int c8 = q & 7;
            win[slot * 1024 + q] =
                *(const u32x4*)(nb + ((size_t)(y * WW + x)) * CC + ((c8 ^ (x & 7)) << 3));
        }
    }
    __syncthreads();                                  // the ONLY barrier

    auto do_tap = [&](int kt, float oy, float ox, float m) {
        const float py = (float)(h - 1 + kt / 3) + oy;
        const float px = (float)(wpix - 1 + kt % 3) + ox;
        const float y0f = floorf(py), x0f = floorf(px);
        const int y0 = (int)y0f, x0 = (int)x0f;
        const float wy = py - y0f, wx = px - x0f;
        const int y1 = y0 + 1, x1 = x0 + 1;
        const bool vy0 = (y0 >= 0) & (y0 < HH);
        const bool vy1 = (y1 >= 0) & (y1 < HH);
        const bool vx0 = (x0 >= 0) & (x0 < WW);
        const bool vx1 = (x1 >= 0) & (x1 < WW);
        const int y0c = min(max(y0, 0), HH - 1), y1c = min(max(y1, 0), HH - 1);
        const int x0c = min(max(x0, 0), WW - 1), x1c = min(max(x1, 0), WW - 1);
        const float wy1 = 1.f - wy, wx1 = 1.f - wx;
        const float c00 = (vy0 && vx0) ? wy1 * wx1 * m : 0.f;
        const float c01 = (vy0 && vx1) ? wy1 * wx  * m : 0.f;
        const float c10 = (vy1 && vx0) ? wy  * wx1 * m : 0.f;
        const float c11 = (vy1 && vx1) ? wy  * wx  * m : 0.f;

        // window slots (clamped for LDS safety; oow lanes reload from global)
        const int s0 = y0c - ys, s1 = y1c - ys;
        const bool in0 = ((unsigned)s0 < 9u);
        const bool in1 = ((unsigned)s1 < 9u);
        const int r0 = (in0 ? s0 : 0) * 1024;
        const int r1 = (in1 ? s1 : 0) * 1024;
        const int bx0 = x0c * 8, sx0 = x0c & 7;
        const int bx1 = x1c * 8, sx1 = x1c & 7;

        #pragma unroll
        for (int ks = 0; ks < 2; ++ks) {
            const int ch = ks * 4 + kq;       // this lane's 8-channel chunk

            u32x4 w00 = win[r0 + bx0 + (ch ^ sx0)];
            u32x4 w01 = win[r0 + bx1 + (ch ^ sx1)];
            u32x4 w10 = win[r1 + bx0 + (ch ^ sx0)];
            u32x4 w11 = win[r1 + bx1 + (ch ^ sx1)];
            if (!in0) {                       // rare: |oy| past window
                w00 = *(const u32x4*)(nb + ((size_t)y0c * WW + x0c) * CC + ch * 8);
                w01 = *(const u32x4*)(nb + ((size_t)y0c * WW + x1c) * CC + ch * 8);
            }
            if (!in1) {
                w10 = *(const u32x4*)(nb + ((size_t)y1c * WW + x0c) * CC + ch * 8);
                w11 = *(const u32x4*)(nb + ((size_t)y1c * WW + x1c) * CC + ch * 8);
            }

            u32x4 pk;
            #pragma unroll
            for (int j = 0; j < 4; ++j) {
                const float a0 = __uint_as_float(w00[j] << 16);
                const float a1 = __uint_as_float(w00[j] & 0xFFFF0000u);
                const float b0 = __uint_as_float(w01[j] << 16);
                const float b1 = __uint_as_float(w01[j] & 0xFFFF0000u);
                const float d0 = __uint_as_float(w10[j] << 16);
                const float d1 = __uint_as_float(w10[j] & 0xFFFF0000u);
                const float e0 = __uint_as_float(w11[j] << 16);
                const float e1 = __uint_as_float(w11[j] & 0xFFFF0000u);
                const float s0f = c00 * a0 + c01 * b0 + c10 * d0 + c11 * e0;
                const float s1f = c00 * a1 + c01 * b1 + c10 * d1 + c11 * e1;
                pk[j] = f32_to_bf16_rne(s0f) | (f32_to_bf16_rne(s1f) << 16);
            }
            const bf16x8 bfrag = __builtin_bit_cast(bf16x8, pk);

            // A-fragments from global (wT2 72KB, L2-resident; VMEM idle here)
            #pragma unroll
            for (int mt = 0; mt < 4; ++mt) {
                const bf16x8 afrag = __builtin_bit_cast(bf16x8,
                    wsrc[(kt * 8 + ks * 4 + kq) * 64 + mt * 16 + l15]);
                acc[mt] = __builtin_amdgcn_mfma_f32_16x16x32_bf16(afrag, bfrag, acc[mt], 0, 0, 0);
            }
        }
    };

    // ---- K loop: fully unrolled, barrier-free ----
    #pragma unroll
    for (int kt = 0; kt < 9; ++kt) {
        do_tap(kt, oyv[kt], oxv[kt], mv[kt]);
    }

    // ---- epilogue: C/D layout col=lane&15 (pixel), row=kq*4+reg (o) ----
    #pragma unroll
    for (int mt = 0; mt < 4; ++mt) {
        const f32x4 bv = *(const f32x4*)(bias + mt * 16 + kq * 4);
        #pragma unroll
        for (int r = 0; r < 4; ++r) {
            const int o = mt * 16 + kq * 4 + r;
            out[((b * 64 + o) * 128 + h) * 128 + wpix] = acc[mt][r] + bv[r];
        }
    }
}

extern "C" void kernel_launch(void* const* d_in, const int* in_sizes, int n_in,
                              void* d_out, int out_size, void* d_ws, size_t ws_size,
                              hipStream_t stream)
{
    const float* input  = (const float*)d_in[0];
    // d_in[1] = depth, unused by the reference
    const float* offset = (const float*)d_in[2];
    const float* mask   = (const float*)d_in[3];
    const float* weight = (const float*)d_in[4];
    const float* bias   = (const float*)d_in[5];
    float* out = (float*)d_out;

    unsigned short* nhwc = (unsigned short*)d_ws;                    // 8.39 MB
    unsigned short* wT2  = nhwc + (size_t)4 * HW * CC;               // 73728 B

    prep_fused12<<<dim3(2066), dim3(256), 0, stream>>>(input, nhwc, weight, wT2);
    ddc_win12<<<dim3(256), dim3(1024), 0, stream>>>(nhwc, wT2, offset, mask, bias, out);
}